// Round 9
// baseline (97.376 us; speedup 1.0000x reference)
//
#include <hip/hip_runtime.h>
#include <hip/hip_bf16.h>
#include <cstddef>

// Problem constants (match reference setup_inputs)
#define NNODES 50000
#define NBW    32      // neighbor width
#define NFEAT  128
#define NHID   64
#define EDIM   32
#define NMETA  3
#define NCLASS 8
#define BB     10000
#define SS     32      // n_sample (== 32 in setup)

// ---------------- workspace layout (float units) ----------------
// HKI  [3][50000][64] u32 (lvl0|lvl1 packed bf16): 0 .. 9,600,000
// hkaI [3][50000][2] f32  : 9,600,000 .. 9,900,000
// wq1v [3][128] f32       : 9,900,000 .. 9,900,384
// wq2v [3][64]  f32       : 9,900,384 .. 9,900,576
// Bf   [6][4][4][64][8] bf16 (frag-ordered Wk): 9,900,576 .. 9,925,152
#define OFF_HKA   9600000
#define OFF_WQ1V  9900000
#define OFF_WQ2V  9900384
#define OFF_WBF   9900576

#define NGEMMBLK  782    // ceil(NNODES/64)

typedef __attribute__((ext_vector_type(8))) short bf16x8;
typedef __attribute__((ext_vector_type(4))) float f32x4;

static __device__ __forceinline__ unsigned short f2bf(float x) {
    unsigned u = __float_as_uint(x);
    return (unsigned short)((u + 0x7fffu + ((u >> 16) & 1u)) >> 16);   // RNE
}
static __device__ __forceinline__ float rdlane_f(float v, int l) {
    return __int_as_float(__builtin_amdgcn_readlane(__float_as_int(v), l));
}

// K0: prep = wqv (blocks 24..26) + wconv (blocks 0..23)
__global__ void prep_kernel(const float* __restrict__ Wq1, const float* __restrict__ a1,
                            const float* __restrict__ Wq2, const float* __restrict__ a2,
                            const float* __restrict__ Wk1, const float* __restrict__ Wk2,
                            float* __restrict__ wq1v, float* __restrict__ wq2v,
                            unsigned short* __restrict__ Bf)
{
    int blk = blockIdx.x, t = threadIdx.x;
    if (blk < 24) {
        // wconv: Bf[mat][kk][t4][lane][j] = bf16(W[mat][kk*32+(lane>>4)*8+j][t4*16+(lane&15)])
        int id = blk * 256 + t;                 // 0 .. 6143
        int lane = id & 63;
        int t4 = (id >> 6) & 3;
        int kk = (id >> 8) & 3;
        int mat = id >> 10;
        const float* W = (mat < 3) ? (Wk1 + (size_t)mat * 8192)
                                   : (Wk2 + (size_t)(mat - 3) * 8192);
        int c  = t4 * 16 + (lane & 15);
        int kb = kk * 32 + (lane >> 4) * 8;
        unsigned short* dst = Bf + (size_t)id * 8;
        #pragma unroll
        for (int j = 0; j < 8; ++j) dst[j] = f2bf(W[(size_t)(kb + j) * 64 + c]);
    } else {
        int m = blk - 24;
        if (t < 128) {
            float acc = 0.f;
            const float* w = Wq1 + (m * 128 + t) * 64;
            const float* a = a1 + m * 160;
            #pragma unroll 8
            for (int c = 0; c < 64; ++c) acc += w[c] * a[c];
            wq1v[m * 128 + t] = acc;
        } else if (t < 192) {
            int f = t - 128;
            float acc = 0.f;
            const float* w = Wq2 + (m * 64 + f) * 64;
            const float* a = a2 + m * 160;
            #pragma unroll 8
            for (int c = 0; c < 64; ++c) acc += w[c] * a[c];
            wq2v[m * 64 + f] = acc;
        }
    }
}

// K1: MFMA GEMM, 3 metapaths x 2 levels per block (node_emb staged once).
// HKI[mm][n][c] = u32( bf16(lvl0) | bf16(lvl1)<<16 ); hkaI[mm][n][0/1] = row . ak
__global__ __launch_bounds__(256) void hk_mfma6(const float* __restrict__ node_emb,
                                                const unsigned short* __restrict__ Bf,
                                                const float* __restrict__ a1,
                                                const float* __restrict__ a2,
                                                unsigned* __restrict__ HKI,
                                                float* __restrict__ hkaI)
{
    __shared__ char lds_a[64 * 256];   // [64 rows][128 bf16], XOR-swizzled
    int nbase = blockIdx.x * 64;
    int t = threadIdx.x;

    // stage: f32 coalesced read -> bf16 -> swizzled LDS write
    #pragma unroll
    for (int i = 0; i < 8; ++i) {
        int fi = (i * 256 + t) * 4;            // float index 0..8191
        int row = fi >> 7, k0 = fi & 127;
        int gn = nbase + row;
        float4 v = (gn < NNODES) ? *(const float4*)(node_emb + (size_t)gn * 128 + k0)
                                 : float4{0.f, 0.f, 0.f, 0.f};
        unsigned lo = (unsigned)f2bf(v.x) | ((unsigned)f2bf(v.y) << 16);
        unsigned hi = (unsigned)f2bf(v.z) | ((unsigned)f2bf(v.w) << 16);
        int byte = (row * 256 + k0 * 2) ^ ((row & 7) << 4);
        *(uint2*)(lds_a + byte) = uint2{lo, hi};
    }
    __syncthreads();

    int w = t >> 6, lane = t & 63;
    int row_l = lane & 15, kgrp = lane >> 4;
    int row = w * 16 + row_l;

    // A-fragments once, reused for all 6 (mm,lvl) GEMMs
    bf16x8 afr[4];
    #pragma unroll
    for (int kk = 0; kk < 4; ++kk) {
        int byte = (row * 256 + kk * 64 + kgrp * 16) ^ ((row_l & 7) << 4);
        afr[kk] = *(const bf16x8*)(lds_a + byte);
    }

    int col0 = lane & 15;
    #pragma unroll
    for (int mm = 0; mm < 3; ++mm) {
        f32x4 acc0[4], acc1[4];
        #pragma unroll
        for (int j = 0; j < 4; ++j) { acc0[j] = f32x4{0,0,0,0}; acc1[j] = f32x4{0,0,0,0}; }
        #pragma unroll
        for (int kk = 0; kk < 4; ++kk) {
            #pragma unroll
            for (int t4 = 0; t4 < 4; ++t4) {
                bf16x8 b0 = *(const bf16x8*)(Bf + ((size_t)((mm * 4 + kk) * 4 + t4) * 64 + lane) * 8);
                bf16x8 b1 = *(const bf16x8*)(Bf + ((size_t)(((3 + mm) * 4 + kk) * 4 + t4) * 64 + lane) * 8);
                acc0[t4] = __builtin_amdgcn_mfma_f32_16x16x32_bf16(afr[kk], b0, acc0[t4], 0, 0, 0);
                acc1[t4] = __builtin_amdgcn_mfma_f32_16x16x32_bf16(afr[kk], b1, acc1[t4], 0, 0, 0);
            }
        }
        const float* ak0 = a1 + mm * 160 + 64;
        const float* ak1 = a2 + mm * 160 + 64;
        float akv0[4], akv1[4];
        #pragma unroll
        for (int t4 = 0; t4 < 4; ++t4) { akv0[t4] = ak0[t4 * 16 + col0]; akv1[t4] = ak1[t4 * 16 + col0]; }
        #pragma unroll
        for (int r = 0; r < 4; ++r) {
            int n = nbase + w * 16 + kgrp * 4 + r;
            float hp0 = acc0[0][r] * akv0[0] + acc0[1][r] * akv0[1]
                      + acc0[2][r] * akv0[2] + acc0[3][r] * akv0[3];
            float hp1 = acc1[0][r] * akv1[0] + acc1[1][r] * akv1[1]
                      + acc1[2][r] * akv1[2] + acc1[3][r] * akv1[3];
            #pragma unroll
            for (int off = 8; off; off >>= 1) {
                hp0 += __shfl_xor(hp0, off, 16);
                hp1 += __shfl_xor(hp1, off, 16);
            }
            if (n < NNODES) {
                unsigned* dst = HKI + ((size_t)mm * NNODES + n) * 64;
                #pragma unroll
                for (int t4 = 0; t4 < 4; ++t4)
                    dst[t4 * 16 + col0] = (unsigned)f2bf(acc0[t4][r])
                                        | ((unsigned)f2bf(acc1[t4][r]) << 16);
                if (col0 == 0)
                    *(float2*)(hkaI + ((size_t)mm * NNODES + n) * 2) = float2{hp0, hp1};
            }
        }
    }
}

// K2: fused attention: per batch row b, 3 waves (one per metapath).
// LDS-pipe-minimal: per-lane edge rows (no transpose), readlane broadcasts
// (no s_nbr/s_att), both-level HK rows batch-loaded upfront.
__global__ __launch_bounds__(192) void fused_kernel(const float* __restrict__ input,
                                                    const int* __restrict__ index,
                                                    const int* __restrict__ edge_index,
                                                    const float* __restrict__ edge_emb,
                                                    const unsigned* __restrict__ HKI,
                                                    const float* __restrict__ hkaI,
                                                    const float* __restrict__ wq1v,
                                                    const float* __restrict__ wq2v,
                                                    const float* __restrict__ a1,
                                                    const float* __restrict__ a2,
                                                    const float* __restrict__ a_mp,
                                                    const float* __restrict__ Wc,
                                                    const float* __restrict__ bc,
                                                    float* __restrict__ out)
{
    __shared__ float s_emb[3][64];
    __shared__ float s_sc[3];

    int t = threadIdx.x, w = t >> 6, lane = t & 63;
    int m = w;
    int b = blockIdx.x;
    int idx = index[b];
    int s = lane & 31;

    // --- neighbor id: lane l holds nbr of row (l&31) ---
    const int* eidx = edge_index + ((size_t)m * NNODES + idx) * NBW;
    int nbr_l = eidx[s];

    // --- edge row (lane&31): 128 B contiguous per lane (4 KB region, L1-merged) ---
    const float4* rowp = (const float4*)(edge_emb + ((size_t)m * NNODES + idx) * (NBW * EDIM))
                       + s * 8;
    float4 ef[8];
    #pragma unroll
    for (int i = 0; i < 8; ++i) ef[i] = rowp[i];

    // --- hka pair for this lane's row ---
    float2 ha = *(const float2*)(hkaI + ((size_t)m * NNODES + nbr_l) * 2);

    // --- batch-load BOTH HK levels for all 32 neighbors (u32 per (j,lane)) ---
    const unsigned* TAB = HKI + (size_t)m * NNODES * 64;
    unsigned h[32];
    #pragma unroll
    for (int j = 0; j < 32; ++j) {
        int nj = __builtin_amdgcn_readlane(nbr_l, j);
        h[j] = TAB[(size_t)nj * 64 + lane];
    }

    // --- edot: lanes<32 -> lvl0 (a1 tail), lanes>=32 -> lvl1 (a2 tail) ---
    const float* aep = ((lane >> 5) ? a2 : a1) + m * 160 + 128;
    float ed = 0.f;
    #pragma unroll
    for (int i = 0; i < 8; ++i) {
        float4 a4 = *(const float4*)(aep + i * 4);
        ed += ef[i].x * a4.x + ef[i].y * a4.y + ef[i].z * a4.z + ef[i].w * a4.w;
    }
    float ed_sw = __shfl_xor(ed, 32, 64);   // lanes<32: lvl1 edot for row s

    // --- hqd1 = input[b] . wq1v[m] (butterfly over 64) ---
    float hv = input[(size_t)b * 128 + lane] * wq1v[m * 128 + lane]
             + input[(size_t)b * 128 + 64 + lane] * wq1v[m * 128 + 64 + lane];
    #pragma unroll
    for (int off = 32; off; off >>= 1) hv += __shfl_xor(hv, off, 64);

    // --- lvl1 attention scores (lanes<32) ---
    float att_l = 0.f;
    {
        float sc = hv + ha.x + ed;
        sc = sc > 0.f ? sc : 0.2f * sc;
        float mx = sc;
        #pragma unroll
        for (int off = 16; off; off >>= 1) mx = fmaxf(mx, __shfl_xor(mx, off, 32));
        float p = expf(sc - mx);
        float sm = p;
        #pragma unroll
        for (int off = 16; off; off >>= 1) sm += __shfl_xor(sm, off, 32);
        att_l = p / sm;   // valid in lanes<32
    }

    // --- lvl1 aggregation: readlane broadcast + low-half bf16 of h ---
    float acc = 0.f;
    #pragma unroll
    for (int j = 0; j < 32; ++j)
        acc += rdlane_f(att_l, j) * __uint_as_float(h[j] << 16);
    float x = acc > 0.f ? acc : expm1f(acc);   // elu

    // --- hqd2 = x . wq2v[m] ---
    float hv2 = x * wq2v[m * 64 + lane];
    #pragma unroll
    for (int off = 32; off; off >>= 1) hv2 += __shfl_xor(hv2, off, 64);

    // --- lvl2 attention scores (lanes<32) ---
    float att2_l = 0.f;
    {
        float sc = hv2 + ha.y + ed_sw;
        sc = sc > 0.f ? sc : 0.2f * sc;
        float mx = sc;
        #pragma unroll
        for (int off = 16; off; off >>= 1) mx = fmaxf(mx, __shfl_xor(mx, off, 32));
        float p = expf(sc - mx);
        float sm = p;
        #pragma unroll
        for (int off = 16; off; off >>= 1) sm += __shfl_xor(sm, off, 32);
        att2_l = p / sm;
    }

    // --- lvl2 aggregation: high-half bf16 of h ---
    acc = 0.f;
    #pragma unroll
    for (int j = 0; j < 32; ++j)
        acc += rdlane_f(att2_l, j) * __uint_as_float(h[j] & 0xffff0000u);
    float emb_c = acc > 0.f ? acc : expm1f(acc);
    s_emb[m][lane] = emb_c;

    // --- e[m] = leaky(emb . a_mp) ---
    float ev = emb_c * a_mp[lane];
    #pragma unroll
    for (int off = 32; off; off >>= 1) ev += __shfl_xor(ev, off, 64);
    if (lane == 0) s_sc[m] = ev > 0.f ? ev : 0.2f * ev;
    __syncthreads();   // single block barrier

    // --- fusion + classifier on wave 0 ---
    if (w == 0) {
        float e0 = s_sc[0], e1 = s_sc[1], e2 = s_sc[2];
        float mx = fmaxf(e0, fmaxf(e1, e2));
        float p0 = expf(e0 - mx), p1 = expf(e1 - mx), p2 = expf(e2 - mx);
        float sm = p0 + p1 + p2;
        float fused = (p0 * s_emb[0][lane] + p1 * s_emb[1][lane] + p2 * s_emb[2][lane]) / sm;

        float lg[NCLASS];
        #pragma unroll
        for (int j = 0; j < NCLASS; ++j) {
            float v = fused * Wc[lane * NCLASS + j];
            #pragma unroll
            for (int off = 32; off; off >>= 1) v += __shfl_xor(v, off, 64);
            lg[j] = fmaxf(v + bc[j], 0.f);     // relu(logits)
        }
        float m8 = lg[0];
        #pragma unroll
        for (int j = 1; j < NCLASS; ++j) m8 = fmaxf(m8, lg[j]);
        float se = 0.f;
        #pragma unroll
        for (int j = 0; j < NCLASS; ++j) se += expf(lg[j] - m8);
        float ls = logf(se);
        #pragma unroll
        for (int j = 0; j < NCLASS; ++j) {
            if (lane == j) out[(size_t)b * NCLASS + j] = lg[j] - m8 - ls;
        }
    }
}

extern "C" void kernel_launch(void* const* d_in, const int* in_sizes, int n_in,
                              void* d_out, int out_size, void* d_ws, size_t ws_size,
                              hipStream_t stream)
{
    const float* input     = (const float*)d_in[0];
    const int*   index     = (const int*)d_in[1];
    const float* node_emb  = (const float*)d_in[2];
    const int*   edge_index= (const int*)d_in[3];
    const float* edge_emb  = (const float*)d_in[4];
    // d_in[5] = n_sample (scalar 32, hardcoded as SS)
    const float* Wq1 = (const float*)d_in[6];
    const float* Wk1 = (const float*)d_in[7];
    const float* a1  = (const float*)d_in[8];
    const float* Wq2 = (const float*)d_in[9];
    const float* Wk2 = (const float*)d_in[10];
    const float* a2  = (const float*)d_in[11];
    const float* a_mp= (const float*)d_in[12];
    const float* Wc  = (const float*)d_in[13];
    const float* bc  = (const float*)d_in[14];

    float* ws = (float*)d_ws;
    unsigned* HKI = (unsigned*)d_ws;
    float* hkaI = ws + OFF_HKA;
    float* wq1v = ws + OFF_WQ1V;
    float* wq2v = ws + OFF_WQ2V;
    unsigned short* Bf = (unsigned short*)(ws + OFF_WBF);

    prep_kernel<<<dim3(27), dim3(256), 0, stream>>>(Wq1, a1, Wq2, a2, Wk1, Wk2,
                                                    wq1v, wq2v, Bf);
    hk_mfma6<<<dim3(NGEMMBLK), dim3(256), 0, stream>>>(
        node_emb, Bf, a1, a2, HKI, hkaI);
    fused_kernel<<<dim3(BB), dim3(192), 0, stream>>>(
        input, index, edge_index, edge_emb, HKI, hkaI, wq1v, wq2v,
        a1, a2, a_mp, Wc, bc, (float*)d_out);
}

// Round 10
// 94.065 us; speedup vs baseline: 1.0352x; 1.0352x over previous
//
#include <hip/hip_runtime.h>
#include <hip/hip_bf16.h>
#include <cstddef>

// Problem constants (match reference setup_inputs)
#define NNODES 50000
#define NBW    32      // neighbor width
#define NFEAT  128
#define NHID   64
#define EDIM   32
#define NMETA  3
#define NCLASS 8
#define BB     10000
#define SS     32      // n_sample (== 32 in setup)

// ---------------- workspace layout (float units) ----------------
// HKI  [3][50000][64] u32 (lvl0|lvl1 packed bf16): 0 .. 9,600,000
// hkaI [3][50000][2] f32  : 9,600,000 .. 9,900,000
// wq1v [3][128] f32       : 9,900,000 .. 9,900,384
// wq2v [3][64]  f32       : 9,900,384 .. 9,900,576
// Bf   [6][4][4][64][8] bf16 (frag-ordered Wk): 9,900,576 .. 9,925,152
#define OFF_HKA   9600000
#define OFF_WQ1V  9900000
#define OFF_WQ2V  9900384
#define OFF_WBF   9900576

#define NGEMMBLK  782    // ceil(NNODES/64)

typedef __attribute__((ext_vector_type(8))) short bf16x8;
typedef __attribute__((ext_vector_type(4))) float f32x4;

static __device__ __forceinline__ unsigned short f2bf(float x) {
    unsigned u = __float_as_uint(x);
    return (unsigned short)((u + 0x7fffu + ((u >> 16) & 1u)) >> 16);   // RNE
}
static __device__ __forceinline__ float rdlane_f(float v, int l) {
    return __int_as_float(__builtin_amdgcn_readlane(__float_as_int(v), l));
}

// K0: prep = wqv (blocks 24..26) + wconv (blocks 0..23)
__global__ void prep_kernel(const float* __restrict__ Wq1, const float* __restrict__ a1,
                            const float* __restrict__ Wq2, const float* __restrict__ a2,
                            const float* __restrict__ Wk1, const float* __restrict__ Wk2,
                            float* __restrict__ wq1v, float* __restrict__ wq2v,
                            unsigned short* __restrict__ Bf)
{
    int blk = blockIdx.x, t = threadIdx.x;
    if (blk < 24) {
        // wconv: Bf[mat][kk][t4][lane][j] = bf16(W[mat][kk*32+(lane>>4)*8+j][t4*16+(lane&15)])
        int id = blk * 256 + t;                 // 0 .. 6143
        int lane = id & 63;
        int t4 = (id >> 6) & 3;
        int kk = (id >> 8) & 3;
        int mat = id >> 10;
        const float* W = (mat < 3) ? (Wk1 + (size_t)mat * 8192)
                                   : (Wk2 + (size_t)(mat - 3) * 8192);
        int c  = t4 * 16 + (lane & 15);
        int kb = kk * 32 + (lane >> 4) * 8;
        unsigned short* dst = Bf + (size_t)id * 8;
        #pragma unroll
        for (int j = 0; j < 8; ++j) dst[j] = f2bf(W[(size_t)(kb + j) * 64 + c]);
    } else {
        int m = blk - 24;
        if (t < 128) {
            float acc = 0.f;
            const float* w = Wq1 + (m * 128 + t) * 64;
            const float* a = a1 + m * 160;
            #pragma unroll 8
            for (int c = 0; c < 64; ++c) acc += w[c] * a[c];
            wq1v[m * 128 + t] = acc;
        } else if (t < 192) {
            int f = t - 128;
            float acc = 0.f;
            const float* w = Wq2 + (m * 64 + f) * 64;
            const float* a = a2 + m * 160;
            #pragma unroll 8
            for (int c = 0; c < 64; ++c) acc += w[c] * a[c];
            wq2v[m * 64 + f] = acc;
        }
    }
}

// K1: MFMA GEMM, 3 metapaths x 2 levels per block (node_emb staged once).
// HKI[mm][n][c] = u32( bf16(lvl0) | bf16(lvl1)<<16 ); hkaI[mm][n][0/1] = row . ak
__global__ __launch_bounds__(256) void hk_mfma6(const float* __restrict__ node_emb,
                                                const unsigned short* __restrict__ Bf,
                                                const float* __restrict__ a1,
                                                const float* __restrict__ a2,
                                                unsigned* __restrict__ HKI,
                                                float* __restrict__ hkaI)
{
    __shared__ char lds_a[64 * 256];   // [64 rows][128 bf16], XOR-swizzled
    int nbase = blockIdx.x * 64;
    int t = threadIdx.x;

    // stage: f32 coalesced read -> bf16 -> swizzled LDS write
    #pragma unroll
    for (int i = 0; i < 8; ++i) {
        int fi = (i * 256 + t) * 4;            // float index 0..8191
        int row = fi >> 7, k0 = fi & 127;
        int gn = nbase + row;
        float4 v = (gn < NNODES) ? *(const float4*)(node_emb + (size_t)gn * 128 + k0)
                                 : float4{0.f, 0.f, 0.f, 0.f};
        unsigned lo = (unsigned)f2bf(v.x) | ((unsigned)f2bf(v.y) << 16);
        unsigned hi = (unsigned)f2bf(v.z) | ((unsigned)f2bf(v.w) << 16);
        int byte = (row * 256 + k0 * 2) ^ ((row & 7) << 4);
        *(uint2*)(lds_a + byte) = uint2{lo, hi};
    }
    __syncthreads();

    int w = t >> 6, lane = t & 63;
    int row_l = lane & 15, kgrp = lane >> 4;
    int row = w * 16 + row_l;

    // A-fragments once, reused for all 6 (mm,lvl) GEMMs
    bf16x8 afr[4];
    #pragma unroll
    for (int kk = 0; kk < 4; ++kk) {
        int byte = (row * 256 + kk * 64 + kgrp * 16) ^ ((row_l & 7) << 4);
        afr[kk] = *(const bf16x8*)(lds_a + byte);
    }

    int col0 = lane & 15;
    #pragma unroll
    for (int mm = 0; mm < 3; ++mm) {
        f32x4 acc0[4], acc1[4];
        #pragma unroll
        for (int j = 0; j < 4; ++j) { acc0[j] = f32x4{0,0,0,0}; acc1[j] = f32x4{0,0,0,0}; }
        #pragma unroll
        for (int kk = 0; kk < 4; ++kk) {
            #pragma unroll
            for (int t4 = 0; t4 < 4; ++t4) {
                bf16x8 b0 = *(const bf16x8*)(Bf + ((size_t)((mm * 4 + kk) * 4 + t4) * 64 + lane) * 8);
                bf16x8 b1 = *(const bf16x8*)(Bf + ((size_t)(((3 + mm) * 4 + kk) * 4 + t4) * 64 + lane) * 8);
                acc0[t4] = __builtin_amdgcn_mfma_f32_16x16x32_bf16(afr[kk], b0, acc0[t4], 0, 0, 0);
                acc1[t4] = __builtin_amdgcn_mfma_f32_16x16x32_bf16(afr[kk], b1, acc1[t4], 0, 0, 0);
            }
        }
        const float* ak0 = a1 + mm * 160 + 64;
        const float* ak1 = a2 + mm * 160 + 64;
        float akv0[4], akv1[4];
        #pragma unroll
        for (int t4 = 0; t4 < 4; ++t4) { akv0[t4] = ak0[t4 * 16 + col0]; akv1[t4] = ak1[t4 * 16 + col0]; }
        #pragma unroll
        for (int r = 0; r < 4; ++r) {
            int n = nbase + w * 16 + kgrp * 4 + r;
            float hp0 = acc0[0][r] * akv0[0] + acc0[1][r] * akv0[1]
                      + acc0[2][r] * akv0[2] + acc0[3][r] * akv0[3];
            float hp1 = acc1[0][r] * akv1[0] + acc1[1][r] * akv1[1]
                      + acc1[2][r] * akv1[2] + acc1[3][r] * akv1[3];
            #pragma unroll
            for (int off = 8; off; off >>= 1) {
                hp0 += __shfl_xor(hp0, off, 16);
                hp1 += __shfl_xor(hp1, off, 16);
            }
            if (n < NNODES) {
                unsigned* dst = HKI + ((size_t)mm * NNODES + n) * 64;
                #pragma unroll
                for (int t4 = 0; t4 < 4; ++t4)
                    dst[t4 * 16 + col0] = (unsigned)f2bf(acc0[t4][r])
                                        | ((unsigned)f2bf(acc1[t4][r]) << 16);
                if (col0 == 0)
                    *(float2*)(hkaI + ((size_t)mm * NNODES + n) * 2) = float2{hp0, hp1};
            }
        }
    }
}

// K2: fused attention: per batch row b, 3 waves (one per metapath).
// R8 structure + scalar (SGPR) neighbor list for the h-gather, short classifier tail.
__global__ __launch_bounds__(192, 5) void fused_kernel(const float* __restrict__ input,
                                                    const int* __restrict__ index,
                                                    const int* __restrict__ edge_index,
                                                    const float* __restrict__ edge_emb,
                                                    const unsigned* __restrict__ HKI,
                                                    const float* __restrict__ hkaI,
                                                    const float* __restrict__ wq1v,
                                                    const float* __restrict__ wq2v,
                                                    const float* __restrict__ a1,
                                                    const float* __restrict__ a2,
                                                    const float* __restrict__ a_mp,
                                                    const float* __restrict__ Wc,
                                                    const float* __restrict__ bc,
                                                    float* __restrict__ out)
{
    __shared__ float s_e[3][32][33];   // edge rows, transposed (wave-private)
    __shared__ float s_att[3][32];
    __shared__ float s_ed1[3][32];
    __shared__ float s_emb[3][64];
    __shared__ float s_sc[3];

    int t = threadIdx.x, lane = t & 63;
    int m = __builtin_amdgcn_readfirstlane(t >> 6);   // wave-uniform metapath
    int w = m;
    int b = blockIdx.x;
    int idx = __builtin_amdgcn_readfirstlane(index[b]);
    int s = lane & 31;

    // --- neighbor list: wave-uniform pointer -> scalar loads (SGPR) ---
    const int* eidx = edge_index + ((size_t)m * NNODES + idx) * NBW;
    int nbr_l = eidx[s];               // per-lane copy for hka

    // --- edge rows: contiguous 4KB, coalesced float4 (HBM) ---
    const float4* src = (const float4*)(edge_emb + ((size_t)m * NNODES + idx) * (NBW * EDIM));
    float4 ef[4];
    #pragma unroll
    for (int i = 0; i < 4; ++i) ef[i] = src[i * 64 + lane];

    // --- hka pair (lvl-interleaved) for this lane's row ---
    float2 ha = *(const float2*)(hkaI + ((size_t)m * NNODES + nbr_l) * 2);

    // --- batch-load BOTH HK levels for all 32 neighbors; addresses from SGPRs ---
    const unsigned* TAB = HKI + (size_t)m * NNODES * 64;
    unsigned h[32];
    #pragma unroll
    for (int j = 0; j < 32; ++j) {
        int nj = eidx[j];              // uniform -> s_load, no LDS/VALU chain
        h[j] = TAB[(size_t)nj * 64 + lane];
    }

    // --- stage edge rows transposed (wave-private LDS; in-order within wave) ---
    #pragma unroll
    for (int i = 0; i < 4; ++i) {
        int li = i * 64 + lane;
        int r = li >> 3, c4 = (li & 7) * 4;
        s_e[w][r][c4]     = ef[i].x;
        s_e[w][r][c4 + 1] = ef[i].y;
        s_e[w][r][c4 + 2] = ef[i].z;
        s_e[w][r][c4 + 3] = ef[i].w;
    }

    // --- edots: lanes 0-31 lvl0 (reg), lanes 32-63 lvl1 (to LDS) ---
    int lvl = lane >> 5;
    const float* ae = (lvl ? a2 : a1) + m * 160 + 128;
    float ed = 0.f;
    #pragma unroll
    for (int k = 0; k < 32; ++k) ed += s_e[w][s][k] * ae[k];
    if (lvl) s_ed1[w][s] = ed;

    // --- hqd1 = input[b] . wq1v[m] (global reads, L1-shared across waves) ---
    float hv = input[(size_t)b * 128 + lane] * wq1v[m * 128 + lane]
             + input[(size_t)b * 128 + 64 + lane] * wq1v[m * 128 + 64 + lane];
    #pragma unroll
    for (int off = 32; off; off >>= 1) hv += __shfl_xor(hv, off, 64);

    // --- lvl1 attention scores (lanes<32) ---
    if (lane < 32) {
        float sc = hv + ha.x + ed;
        sc = sc > 0.f ? sc : 0.2f * sc;
        float mx = sc;
        #pragma unroll
        for (int off = 16; off; off >>= 1) mx = fmaxf(mx, __shfl_xor(mx, off, 32));
        float p = expf(sc - mx);
        float sm = p;
        #pragma unroll
        for (int off = 16; off; off >>= 1) sm += __shfl_xor(sm, off, 32);
        s_att[w][lane] = p / sm;
    }

    // --- lvl1 aggregation: registers (low half of h) + LDS broadcast weights ---
    float acc = 0.f;
    #pragma unroll
    for (int j = 0; j < 32; ++j)
        acc += s_att[w][j] * __uint_as_float(h[j] << 16);
    float x = acc > 0.f ? acc : expm1f(acc);   // elu

    // --- hqd2 = x . wq2v[m] ---
    float hv2 = x * wq2v[m * 64 + lane];
    #pragma unroll
    for (int off = 32; off; off >>= 1) hv2 += __shfl_xor(hv2, off, 64);

    // --- lvl2 attention scores (lanes<32) ---
    if (lane < 32) {
        float sc = hv2 + ha.y + s_ed1[w][lane];
        sc = sc > 0.f ? sc : 0.2f * sc;
        float mx = sc;
        #pragma unroll
        for (int off = 16; off; off >>= 1) mx = fmaxf(mx, __shfl_xor(mx, off, 32));
        float p = expf(sc - mx);
        float sm = p;
        #pragma unroll
        for (int off = 16; off; off >>= 1) sm += __shfl_xor(sm, off, 32);
        s_att[w][lane] = p / sm;
    }

    // --- lvl2 aggregation: high-half bf16 of h ---
    acc = 0.f;
    #pragma unroll
    for (int j = 0; j < 32; ++j)
        acc += s_att[w][j] * __uint_as_float(h[j] & 0xffff0000u);
    float emb_c = acc > 0.f ? acc : expm1f(acc);
    s_emb[w][lane] = emb_c;

    // --- e[m] = leaky(emb . a_mp) ---
    float ev = emb_c * a_mp[lane];
    #pragma unroll
    for (int off = 32; off; off >>= 1) ev += __shfl_xor(ev, off, 64);
    if (lane == 0) s_sc[w] = ev > 0.f ? ev : 0.2f * ev;
    __syncthreads();   // single block barrier

    // --- fusion + classifier on wave 0 (8-lane-group dot, short tail) ---
    if (w == 0) {
        float e0 = s_sc[0], e1 = s_sc[1], e2 = s_sc[2];
        float mx3 = fmaxf(e0, fmaxf(e1, e2));
        float p0 = expf(e0 - mx3), p1 = expf(e1 - mx3), p2 = expf(e2 - mx3);
        float sminv = 1.f / (p0 + p1 + p2);

        int g = lane >> 3, r = lane & 7;
        float v = 0.f;
        #pragma unroll
        for (int k = 0; k < 8; ++k) {
            int c = r + 8 * k;
            float fc = (p0 * s_emb[0][c] + p1 * s_emb[1][c] + p2 * s_emb[2][c]) * sminv;
            v += fc * Wc[c * NCLASS + g];
        }
        v += __shfl_xor(v, 1, 64);
        v += __shfl_xor(v, 2, 64);
        v += __shfl_xor(v, 4, 64);
        float lg = fmaxf(v + bc[g], 0.f);      // all lanes of group g hold lg[g]

        float l0 = rdlane_f(lg, 0),  l1 = rdlane_f(lg, 8),  l2 = rdlane_f(lg, 16), l3 = rdlane_f(lg, 24);
        float l4 = rdlane_f(lg, 32), l5 = rdlane_f(lg, 40), l6 = rdlane_f(lg, 48), l7 = rdlane_f(lg, 56);
        float m8 = fmaxf(fmaxf(fmaxf(l0, l1), fmaxf(l2, l3)),
                         fmaxf(fmaxf(l4, l5), fmaxf(l6, l7)));
        float se = expf(l0 - m8) + expf(l1 - m8) + expf(l2 - m8) + expf(l3 - m8)
                 + expf(l4 - m8) + expf(l5 - m8) + expf(l6 - m8) + expf(l7 - m8);
        float ls = logf(se);
        if (lane < 8) {
            float lj = lane == 0 ? l0 : lane == 1 ? l1 : lane == 2 ? l2 : lane == 3 ? l3
                     : lane == 4 ? l4 : lane == 5 ? l5 : lane == 6 ? l6 : l7;
            out[(size_t)b * NCLASS + lane] = lj - m8 - ls;
        }
    }
}

extern "C" void kernel_launch(void* const* d_in, const int* in_sizes, int n_in,
                              void* d_out, int out_size, void* d_ws, size_t ws_size,
                              hipStream_t stream)
{
    const float* input     = (const float*)d_in[0];
    const int*   index     = (const int*)d_in[1];
    const float* node_emb  = (const float*)d_in[2];
    const int*   edge_index= (const int*)d_in[3];
    const float* edge_emb  = (const float*)d_in[4];
    // d_in[5] = n_sample (scalar 32, hardcoded as SS)
    const float* Wq1 = (const float*)d_in[6];
    const float* Wk1 = (const float*)d_in[7];
    const float* a1  = (const float*)d_in[8];
    const float* Wq2 = (const float*)d_in[9];
    const float* Wk2 = (const float*)d_in[10];
    const float* a2  = (const float*)d_in[11];
    const float* a_mp= (const float*)d_in[12];
    const float* Wc  = (const float*)d_in[13];
    const float* bc  = (const float*)d_in[14];

    float* ws = (float*)d_ws;
    unsigned* HKI = (unsigned*)d_ws;
    float* hkaI = ws + OFF_HKA;
    float* wq1v = ws + OFF_WQ1V;
    float* wq2v = ws + OFF_WQ2V;
    unsigned short* Bf = (unsigned short*)(ws + OFF_WBF);

    prep_kernel<<<dim3(27), dim3(256), 0, stream>>>(Wq1, a1, Wq2, a2, Wk1, Wk2,
                                                    wq1v, wq2v, Bf);
    hk_mfma6<<<dim3(NGEMMBLK), dim3(256), 0, stream>>>(
        node_emb, Bf, a1, a2, HKI, hkaI);
    fused_kernel<<<dim3(BB), dim3(192), 0, stream>>>(
        input, index, edge_index, edge_emb, HKI, hkaI, wq1v, wq2v,
        a1, a2, a_mp, Wc, bc, (float*)d_out);
}